// Round 5
// baseline (653.948 us; speedup 1.0000x reference)
//
#include <hip/hip_runtime.h>
#include <hip/hip_bf16.h>

// hierarch_sep_loss: preds [2, N, 100] fp32 probs, labs [2, N] int, cen [2, N] int
// out[0] = sum over mods of:
//   (n_u/N) * (-sum_{cen==0} log(p[i,lab_i]+EPS) / max(1,n_u))
// + (n_c/N) * (-sum_{cen==1} log(sum_{j>lab0_i} p[i,j]+EPS) / max(1,n_c)) * 0.5
//
// Ledger (structure -> total us): R6 gather 480.5 | R8 batch-4 481.6 |
// R10 wave-transposed 495.4 | R9 lane-linear stream 525.5 | R7 stream 565.9.
// Conclusion: the gather floor is structure-independent (traffic/granule
// bound at the ~2.9 TB/s scatter plateau); every restructure only ADDED
// overhead. R11: keep R6's main loop BYTE-IDENTICAL; delete the epilogue
// overhead instead — fused atomic finish:
//  - per-block partials -> 4x atomicAdd(double) + 4x atomicAdd(uint)
//    (8192 atomics total, negligible contention; device-scope by default)
//  - last-block-done counter (__threadfence ordered) computes the final
//    scalar and writes out[0] -> hsl_final launch + 98KB round-trip gone.
//  - workspace: 64B zeroed via hipMemsetAsync (graph-capture safe).

#define HSL_EPS 1e-10f
#define NBLK 2048

__global__ __launch_bounds__(256, 8) void hsl_main(
    const float* __restrict__ preds,
    const int*   __restrict__ labs,
    const int*   __restrict__ cen,
    double*       __restrict__ gsums,  // [4] device totals (zeroed)
    unsigned int* __restrict__ gcnts,  // [4]
    unsigned int* __restrict__ done,   // [1] finished-block counter
    float*        __restrict__ out,
    long long N)
{
    const long long R = 2LL * N;
    const int q = threadIdx.x & 3;               // lane within 4-lane row group
    const long long g0 = ((long long)blockIdx.x * blockDim.x + threadIdx.x) >> 2;
    const long long ng = ((long long)gridDim.x * blockDim.x) >> 2;

    double usum[2] = {0.0, 0.0};
    double csum[2] = {0.0, 0.0};
    unsigned int ucnt[2] = {0u, 0u};
    unsigned int ccnt[2] = {0u, 0u};

    for (long long r = g0; r < R; r += ng) {
        const int m = (r >= N) ? 1 : 0;
        const long long i0 = r - (long long)m * N;
        const int c   = cen[r];
        const int lab = labs[r];
        const int t1  = labs[i0] + 1;            // censored: sum over j >= t1, t1 in [1,100]
        const float* rowp = preds + r * 100;

        if (c == 0) {
            // ---- uncensored: single gather, all 4 lanes same addr (1 line) ----
            const float gp = rowp[lab];
            if (q == 0) { usum[m] += (double)logf(gp + HSL_EPS); ucnt[m]++; }
        } else {
            // ---- censored: shorter of prefix/suffix, predicated float4 loads ----
            const bool pre = (t1 <= 50);
            const int b4 = pre ? 0 : (t1 >> 2);  // starting float4 index (16B aligned)
            const float4* rowp4 = (const float4*)rowp;

            float sp = 0.0f;
            #pragma unroll
            for (int k = 0; k < 4; ++k) {
                const int f4 = b4 + 4 * k + q;
                const bool issue = pre ? (4 * f4 < t1) : (f4 <= 24);
                if (issue) {                     // masked lanes: no mem request
                    const float4 v = rowp4[f4];
                    #pragma unroll
                    for (int e = 0; e < 4; ++e) {
                        const int j = 4 * f4 + e;
                        const float p = ((const float*)&v)[e];
                        const bool use = pre ? (j < t1) : (j >= t1);
                        sp += use ? p : 0.0f;
                    }
                }
            }
            // reduce 4 quarter-partials within the group
            sp += __shfl_xor(sp, 1, 64);
            sp += __shfl_xor(sp, 2, 64);
            if (q == 0) {
                const float s = pre ? (1.0f - sp) : sp;
                csum[m] += (double)logf(s + HSL_EPS);
                ccnt[m]++;
            }
        }
    }

    // ---- wave shuffle reduction -> block LDS -> fused atomic finish ----
    #pragma unroll
    for (int off = 32; off > 0; off >>= 1) {
        usum[0] += __shfl_down(usum[0], off, 64);
        csum[0] += __shfl_down(csum[0], off, 64);
        usum[1] += __shfl_down(usum[1], off, 64);
        csum[1] += __shfl_down(csum[1], off, 64);
        ucnt[0] += __shfl_down(ucnt[0], off, 64);
        ccnt[0] += __shfl_down(ccnt[0], off, 64);
        ucnt[1] += __shfl_down(ucnt[1], off, 64);
        ccnt[1] += __shfl_down(ccnt[1], off, 64);
    }

    __shared__ double sh_sums[4][4];
    __shared__ unsigned int sh_cnts[4][4];
    const int waveInBlk = threadIdx.x >> 6;
    const int lane = threadIdx.x & 63;
    if (lane == 0) {
        sh_sums[waveInBlk][0] = usum[0]; sh_sums[waveInBlk][1] = csum[0];
        sh_sums[waveInBlk][2] = usum[1]; sh_sums[waveInBlk][3] = csum[1];
        sh_cnts[waveInBlk][0] = ucnt[0]; sh_cnts[waveInBlk][1] = ccnt[0];
        sh_cnts[waveInBlk][2] = ucnt[1]; sh_cnts[waveInBlk][3] = ccnt[1];
    }
    __syncthreads();
    if (threadIdx.x < 4) {
        const int slot = threadIdx.x;
        double s = 0.0; unsigned int k = 0u;
        for (int w = 0; w < 4; ++w) { s += sh_sums[w][slot]; k += sh_cnts[w][slot]; }
        atomicAdd(&gsums[slot], s);
        atomicAdd(&gcnts[slot], k);
    }
    __threadfence();                  // order this block's atomics before done++
    __syncthreads();

    if (threadIdx.x == 0) {
        const unsigned int prev = atomicAdd(done, 1u);
        if (prev == (unsigned int)gridDim.x - 1u) {
            // last block: all other blocks' atomics are visible (fence+done order)
            double fs[4], fk[4];
            #pragma unroll
            for (int slot = 0; slot < 4; ++slot) {
                fs[slot] = atomicAdd(&gsums[slot], 0.0);           // coherent read
                fk[slot] = (double)atomicAdd(&gcnts[slot], 0u);
            }
            float total = 0.0f;
            const float n = (float)N;
            for (int m = 0; m < 2; ++m) {
                const float nu = (float)fk[2 * m + 0];
                const float nc = (float)fk[2 * m + 1];
                const float us = (float)fs[2 * m + 0];
                const float cs = (float)fs[2 * m + 1];
                const float uncen_loss = -us / fmaxf(1.0f, nu);
                const float cen_loss   = -cs / fmaxf(1.0f, nc);
                total += (nu / n) * uncen_loss + (nc / n) * cen_loss * 0.5f;
            }
            out[0] = total;
        }
    }
}

extern "C" void kernel_launch(void* const* d_in, const int* in_sizes, int n_in,
                              void* d_out, int out_size, void* d_ws, size_t ws_size,
                              hipStream_t stream)
{
    const float* preds = (const float*)d_in[0];
    const int*   labs  = (const int*)d_in[1];
    const int*   cen   = (const int*)d_in[2];
    float* out = (float*)d_out;

    const long long N = (long long)(in_sizes[1] / 2);   // labs flat = 2*N; B=100 hardcoded

    // workspace layout: 4 doubles (32B) | 4 uints (16B) | done counter (4B)
    double*       gsums = (double*)d_ws;
    unsigned int* gcnts = (unsigned int*)((char*)d_ws + 32);
    unsigned int* done  = (unsigned int*)((char*)d_ws + 48);

    hipMemsetAsync(d_ws, 0, 64, stream);   // graph-capture safe
    hsl_main<<<NBLK, 256, 0, stream>>>(preds, labs, cen, gsums, gcnts, done, out, N);
}